// Round 5
// baseline (1008.900 us; speedup 1.0000x reference)
//
#include <hip/hip_runtime.h>
#include <math.h>

// Problem constants (reference: B=32, L=2048)
#define LLEN 2048
#define BATCH 32
#define N_PTS (LLEN - 2)     // 2046 embedded points
#define N_DEATH (LLEN - 3)   // 2045 MST edges / deaths
#define SORT_N 2048
#define TPB 256              // 4 waves, one per SIMD
#define NW 4
#define BIG 1e30f
#define TOPO_BYTES ((size_t)64 * N_DEATH * 4)   // 523,520 B

typedef float v2f __attribute__((ext_vector_type(2)));

// Wave64 unsigned-min via DPP (VALU pipe). Result valid in lane 63.
__device__ __forceinline__ unsigned dpp_umin6(unsigned v) {
    unsigned t;
    t = (unsigned)__builtin_amdgcn_update_dpp(-1, (int)v, 0x111, 0xF, 0xF, false); // row_shr:1
    v = t < v ? t : v;
    t = (unsigned)__builtin_amdgcn_update_dpp(-1, (int)v, 0x112, 0xF, 0xF, false); // row_shr:2
    v = t < v ? t : v;
    t = (unsigned)__builtin_amdgcn_update_dpp(-1, (int)v, 0x114, 0xF, 0xF, false); // row_shr:4
    v = t < v ? t : v;
    t = (unsigned)__builtin_amdgcn_update_dpp(-1, (int)v, 0x118, 0xF, 0xF, false); // row_shr:8
    v = t < v ? t : v;
    t = (unsigned)__builtin_amdgcn_update_dpp(-1, (int)v, 0x142, 0xF, 0xF, false); // row_bcast:15
    v = t < v ? t : v;
    t = (unsigned)__builtin_amdgcn_update_dpp(-1, (int)v, 0x143, 0xF, 0xF, false); // row_bcast:31
    v = t < v ? t : v;
    return v;
}

// ROUND-10: r4 (581 us, calibrated chain: 520 fixed + 32*PT scan) minus the
// post-barrier pp[j] LDS round-trip. With strided ownership idx = s*256+t,
// each wave's argmin vertex is owned by a lane OF THAT WAVE, so the winning
// position is gathered intra-wave BEFORE the barrier:
//   dpp reduce -> readlane(63) -> wave-uniform key wk (SGPR); owner lane
//   = wk&63, slot s_idx = (wk>>8)&7 (idx<=2047 so key bit 11 is 0);
//   every lane selects ps[s_idx] (unrolled cndmask chain), 3x readlane
//   pulls the owner's xyz; lane 0 publishes float4{key,x,y,z}; barrier;
//   min-tree over 4 broadcast float4s carries pos -> pjx/pjy/pjz directly.
// pp[] is now touched only at compaction boundaries (keys keep carrying
// the linear slot id, so compaction/reload logic is unchanged).
// All-visited wave publishes key 0xFFFFFFFF + garbage pos - never wins.
template<int PT, bool FIRST, bool COMPACT>
__device__ __forceinline__ void prim_phase(
    const int t, const int lane, const int wid,
    const int i0, const int i1, const unsigned rem_in,
    float4* __restrict__ pp, float* __restrict__ deaths,
    float4* __restrict__ xs4, unsigned* __restrict__ wtot,
    float& pjx, float& pjy, float& pjz)
{
    v2f px2[PT / 2], py2[PT / 2], pz2[PT / 2];
    unsigned m[PT];
    unsigned vis = 0u;
#pragma unroll
    for (int s = 0; s < PT; ++s) {
        const int idx = s * 256 + t;
        float4 p = pp[idx];
        if (s & 1) { px2[s >> 1].y = p.x; py2[s >> 1].y = p.y; pz2[s >> 1].y = p.z; }
        else       { px2[s >> 1].x = p.x; py2[s >> 1].x = p.y; pz2[s >> 1].x = p.z; }
        if (FIRST) {
            m[s] = 0x7F800000u | (unsigned)idx;           // +inf packed | idx
            if (idx >= (int)rem_in || idx == 0) vis |= 1u << s;  // pads + start
        } else {
            m[s] = __float_as_uint(p.w);                  // carried key
            if (idx >= (int)rem_in) vis |= 1u << s;       // empty slots
        }
    }

#pragma unroll 1
    for (int i = i0; i < i1; ++i) {
        v2f jx = {pjx, pjx}, jy = {pjy, pjy}, jz = {pjz, pjz};
        unsigned lv0 = 0xFFFFFFFFu, lv1 = 0xFFFFFFFFu;
#pragma unroll
        for (int k = 0; k < PT / 2; ++k) {
            v2f dx = px2[k] - jx, dy = py2[k] - jy, dz = pz2[k] - jz;
            v2f d2 = dx * dx + dy * dy + dz * dz;
            unsigned pk0 = (__float_as_uint(d2.x) & 0xFFFFF000u) | (unsigned)((2 * k) * 256 + t);
            unsigned pk1 = (__float_as_uint(d2.y) & 0xFFFFF000u) | (unsigned)((2 * k + 1) * 256 + t);
            unsigned nm0 = m[2 * k] < pk0 ? m[2 * k] : pk0;
            unsigned nm1 = m[2 * k + 1] < pk1 ? m[2 * k + 1] : pk1;
            m[2 * k] = nm0;
            m[2 * k + 1] = nm1;
            unsigned e0 = (unsigned)__builtin_amdgcn_sbfe((int)vis, 2 * k, 1);
            unsigned e1 = (unsigned)__builtin_amdgcn_sbfe((int)vis, 2 * k + 1, 1);
            unsigned c0 = nm0 | e0, c1 = nm1 | e1;
            lv0 = lv0 < c0 ? lv0 : c0;
            lv1 = lv1 < c1 ? lv1 : c1;
        }
        unsigned lv = lv0 < lv1 ? lv0 : lv1;
        unsigned wmin = dpp_umin6(lv);                            // lane 63
        unsigned wk = (unsigned)__builtin_amdgcn_readlane((int)wmin, 63);  // SGPR

        // intra-wave gather of the winning position (owner is in THIS wave)
        const unsigned s_idx = (wk >> 8) & 7u;
        float sx = px2[0].x, sy = py2[0].x, sz = pz2[0].x;
#pragma unroll
        for (int s = 1; s < PT; ++s) {
            bool sel = (s_idx == (unsigned)s);
            sx = sel ? ((s & 1) ? px2[s >> 1].y : px2[s >> 1].x) : sx;
            sy = sel ? ((s & 1) ? py2[s >> 1].y : py2[s >> 1].x) : sy;
            sz = sel ? ((s & 1) ? pz2[s >> 1].y : pz2[s >> 1].x) : sz;
        }
        const int ol = (int)(wk & 63u);
        unsigned ox = (unsigned)__builtin_amdgcn_readlane((int)__float_as_uint(sx), ol);
        unsigned oy = (unsigned)__builtin_amdgcn_readlane((int)__float_as_uint(sy), ol);
        unsigned oz = (unsigned)__builtin_amdgcn_readlane((int)__float_as_uint(sz), ol);

        const int base = (i & 1) * NW;
        if (lane == 0)
            xs4[base + wid] = make_float4(__uint_as_float(wk), __uint_as_float(ox),
                                          __uint_as_float(oy), __uint_as_float(oz));
        // raw barrier: publish write lands before post-release reads (DS
        // FIFO within CU) — pattern HW-proven r2/r4 (absmax=0).
        asm volatile("s_barrier" ::: "memory");
        float4 c0 = xs4[base + 0], c1 = xs4[base + 1];
        float4 c2 = xs4[base + 2], c3 = xs4[base + 3];
        unsigned k0 = __float_as_uint(c0.x), k1 = __float_as_uint(c1.x);
        unsigned k2 = __float_as_uint(c2.x), k3 = __float_as_uint(c3.x);
        bool sA = k1 < k0;
        unsigned kA = sA ? k1 : k0;
        float xA = sA ? c1.y : c0.y, yA = sA ? c1.z : c0.z, zA = sA ? c1.w : c0.w;
        bool sB = k3 < k2;
        unsigned kB = sB ? k3 : k2;
        float xB = sB ? c3.y : c2.y, yB = sB ? c3.z : c2.z, zB = sB ? c3.w : c2.w;
        bool sC = kB < kA;
        unsigned win = sC ? kB : kA;
        pjx = sC ? xB : xA; pjy = sC ? yB : yA; pjz = sC ? zB : zA;
        vis |= (t == (int)(win & 255u)) ? (1u << ((win >> 8) & 7u)) : 0u;
        if (t == 0) deaths[i] = __uint_as_float(win & 0xFFFFF000u); // raw d2
    }

    if (COMPACT) {
        // block-wide compaction: survivors -> pp[0..rem_out) with keys in .w
        const unsigned livemask = ~vis & ((1u << PT) - 1u);
        const unsigned cnt = (unsigned)__popc(livemask);
        unsigned inc = cnt;
#pragma unroll
        for (int d = 1; d < 64; d <<= 1) {
            unsigned tt = (unsigned)__shfl_up((int)inc, d, 64);
            if (lane >= d) inc += tt;
        }
        if (lane == 63) wtot[wid] = inc;         // wave totals
        asm volatile("s_barrier" ::: "memory");  // wtot visible
        unsigned wbase = 0;
#pragma unroll
        for (int w = 0; w < NW; ++w) wbase += (w < wid) ? wtot[w] : 0u;
        unsigned dst = wbase + inc - cnt;        // exclusive prefix, block-wide
#pragma unroll
        for (int s = 0; s < PT; ++s) {
            if ((livemask >> s) & 1u) {
                float xx = (s & 1) ? px2[s >> 1].y : px2[s >> 1].x;
                float yy = (s & 1) ? py2[s >> 1].y : py2[s >> 1].x;
                float zz = (s & 1) ? pz2[s >> 1].y : pz2[s >> 1].x;
                pp[dst] = make_float4(xx, yy, zz,
                                      __uint_as_float((m[s] & 0xFFFFF000u) | dst));
                ++dst;
            }
        }
        asm volatile("s_barrier" ::: "memory");  // compacted pp visible to reload
    }
}

__global__ __launch_bounds__(TPB)
void topo_kernel(const float* __restrict__ pred,
                 const float* __restrict__ tgt,
                 float* __restrict__ topo /* [64][N_DEATH] */,
                 unsigned* __restrict__ ctr,
                 int fuse,
                 float* __restrict__ out) {
    __shared__ float4 pp[SORT_N];        // pos.xyz + (compacted) key in .w
    __shared__ float deaths[SORT_N];     // raw trunc d2 during Prim
    __shared__ __align__(16) float4 xs4[2 * NW];  // [buf][wave] {key,x,y,z}
    __shared__ unsigned wtot[NW];
    __shared__ unsigned lastflag;

    const int b = blockIdx.x;
    const float* x = (b < BATCH) ? (pred + b * LLEN) : (tgt + (b - BATCH) * LLEN);
    const int t = threadIdx.x;
    const int lane = t & 63;
    const int wid = t >> 6;

    // strided fill: idx = s*256+t, coalesced across t
#pragma unroll
    for (int s = 0; s < 8; ++s) {
        int idx = s * 256 + t;
        bool valid = idx < N_PTS;
        float vx = valid ? x[idx]     : 0.f;
        float vy = valid ? x[idx + 1] : 0.f;
        float vz = valid ? x[idx + 2] : 0.f;
        pp[idx] = make_float4(vx, vy, vz, 0.f);
    }
    __syncthreads();   // pp[] visible (real barrier)

    float pjx = x[0], pjy = x[1], pjz = x[2];

    // phase schedule: compact when unvisited-after == 256*PTnext
    prim_phase<8, true,  true >(t, lane, wid, 0,    509,  N_PTS, pp, deaths, xs4, wtot, pjx, pjy, pjz);
    prim_phase<6, false, true >(t, lane, wid, 509,  1021, 1536,  pp, deaths, xs4, wtot, pjx, pjy, pjz);
    prim_phase<4, false, true >(t, lane, wid, 1021, 1533, 1024,  pp, deaths, xs4, wtot, pjx, pjy, pjz);
    prim_phase<2, false, false>(t, lane, wid, 1533, 2045, 512,   pp, deaths, xs4, wtot, pjx, pjy, pjz);

    // pad then bitonic sort DESCENDING on trunc d2 (sqrt monotone)
    if (t < SORT_N - N_DEATH) deaths[N_DEATH + t] = -BIG;
    __syncthreads();

    for (int k = 2; k <= SORT_N; k <<= 1) {
        for (int jj = k >> 1; jj > 0; jj >>= 1) {
#pragma unroll
            for (int s = 0; s < SORT_N / TPB; ++s) {
                int ii = t + s * TPB;
                int ixj = ii ^ jj;
                if (ixj > ii) {
                    float a = deaths[ii], c = deaths[ixj];
                    bool descBlock = ((ii & k) == 0);
                    bool doSwap = descBlock ? (a < c) : (a > c);
                    if (doSwap) { deaths[ii] = c; deaths[ixj] = a; }
                }
            }
            __syncthreads();
        }
    }

    for (int e = t; e < N_DEATH; e += TPB)
        topo[b * N_DEATH + e] = sqrtf(deaths[e]);   // sqrt deferred to here

    if (!fuse) return;

    // ---- fused loss: last-finishing block computes the full reduction ----
    __syncthreads();
    if (t == 0) {
        __threadfence();   // release: make topo visible across XCDs
        unsigned prev = __hip_atomic_fetch_add(ctr, 1u, __ATOMIC_ACQ_REL,
                                               __HIP_MEMORY_SCOPE_AGENT);
        lastflag = (prev == 63u) ? 1u : 0u;
        __threadfence();   // acquire before cross-XCD reads
    }
    __syncthreads();
    if (lastflag == 0u) return;

    float msum = 0.f;
    const float4* p4 = (const float4*)pred;
    const float4* t4 = (const float4*)tgt;
    for (int e = t; e < (BATCH * LLEN) / 4; e += TPB) {   // 16384 float4 pairs
        float4 a = p4[e], c = t4[e];
        float dx = a.x - c.x, dy = a.y - c.y, dz = a.z - c.z, dw = a.w - c.w;
        msum += dx * dx + dy * dy + dz * dz + dw * dw;
    }
    float tsum = 0.f;
    const float4* q4 = (const float4*)topo;
    const int nt4 = (BATCH * N_DEATH) / 4;   // 16360
    for (int e = t; e < nt4; e += TPB) {
        float4 a = q4[e], c = q4[e + nt4];
        float dx = a.x - c.x, dy = a.y - c.y, dz = a.z - c.z, dw = a.w - c.w;
        tsum += dx * dx + dy * dy + dz * dz + dw * dw;
    }
    __shared__ float sm[2][NW];
#pragma unroll
    for (int off = 32; off >= 1; off >>= 1) {
        msum += __shfl_xor(msum, off);
        tsum += __shfl_xor(tsum, off);
    }
    if (lane == 0) { sm[0][wid] = msum; sm[1][wid] = tsum; }
    __syncthreads();
    if (t == 0) {
        float M = 0.f, T = 0.f;
#pragma unroll
        for (int w = 0; w < NW; ++w) { M += sm[0][w]; T += sm[1][w]; }
        out[0] = M / (float)(BATCH * LLEN) + 0.1f * (T / (float)(BATCH * N_DEATH));
    }
}

// Fallback: single-block deterministic reduction (if ws can't hold the counter)
#define RTPB 1024
__global__ __launch_bounds__(RTPB)
void loss_kernel(const float* __restrict__ pred,
                 const float* __restrict__ tgt,
                 const float* __restrict__ topo,
                 float* __restrict__ out) {
    const int t = threadIdx.x;
    float msum = 0.f;
    const float4* p4 = (const float4*)pred;
    const float4* t4 = (const float4*)tgt;
    const int n4 = (BATCH * LLEN) / 4;   // 16384
    for (int e = t; e < n4; e += RTPB) {
        float4 a = p4[e], c = t4[e];
        float dx = a.x - c.x, dy = a.y - c.y, dz = a.z - c.z, dw = a.w - c.w;
        msum += dx * dx + dy * dy + dz * dz + dw * dw;
    }
    float tsum = 0.f;
    const int nt = BATCH * N_DEATH;      // 65440
    for (int e = t; e < nt; e += RTPB) {
        float d = topo[e] - topo[e + nt];
        tsum += d * d;
    }
    __shared__ float sm[2][RTPB / 64];
#pragma unroll
    for (int off = 32; off >= 1; off >>= 1) {
        msum += __shfl_xor(msum, off);
        tsum += __shfl_xor(tsum, off);
    }
    int lane = t & 63, wid = t >> 6;
    if (lane == 0) { sm[0][wid] = msum; sm[1][wid] = tsum; }
    __syncthreads();
    if (t == 0) {
        float M = 0.f, T = 0.f;
#pragma unroll
        for (int w = 0; w < RTPB / 64; ++w) { M += sm[0][w]; T += sm[1][w]; }
        out[0] = M / (float)(BATCH * LLEN) + 0.1f * (T / (float)nt);
    }
}

extern "C" void kernel_launch(void* const* d_in, const int* in_sizes, int n_in,
                              void* d_out, int out_size, void* d_ws, size_t ws_size,
                              hipStream_t stream) {
    const float* pred = (const float*)d_in[0];
    const float* tgt  = (const float*)d_in[1];
    float* topo = (float*)d_ws;
    unsigned* ctr = (unsigned*)((char*)d_ws + TOPO_BYTES);
    const int fuse = (ws_size >= TOPO_BYTES + sizeof(unsigned)) ? 1 : 0;

    if (fuse) hipMemsetAsync(ctr, 0, sizeof(unsigned), stream);  // re-arm per replay

    topo_kernel<<<2 * BATCH, TPB, 0, stream>>>(pred, tgt, topo,
                                               fuse ? ctr : nullptr, fuse,
                                               (float*)d_out);
    if (!fuse)
        loss_kernel<<<1, RTPB, 0, stream>>>(pred, tgt, topo, (float*)d_out);
}

// Round 6
// 698.355 us; speedup vs baseline: 1.4447x; 1.4447x over previous
//
#include <hip/hip_runtime.h>
#include <math.h>

// Problem constants (reference: B=32, L=2048)
#define LLEN 2048
#define BATCH 32
#define N_PTS (LLEN - 2)     // 2046 embedded points
#define N_DEATH (LLEN - 3)   // 2045 MST edges / deaths
#define SORT_N 2048
#define TPB 512              // 8 waves, 2 per SIMD (r6: TLP to hide exchange latency)
#define NW 8
#define BIG 1e30f
#define TOPO_BYTES ((size_t)64 * N_DEATH * 4)   // 523,520 B

// Wave64 unsigned-min via DPP (VALU pipe). Result valid in lane 63.
__device__ __forceinline__ unsigned dpp_umin6(unsigned v) {
    unsigned t;
    t = (unsigned)__builtin_amdgcn_update_dpp(-1, (int)v, 0x111, 0xF, 0xF, false); // row_shr:1
    v = t < v ? t : v;
    t = (unsigned)__builtin_amdgcn_update_dpp(-1, (int)v, 0x112, 0xF, 0xF, false); // row_shr:2
    v = t < v ? t : v;
    t = (unsigned)__builtin_amdgcn_update_dpp(-1, (int)v, 0x114, 0xF, 0xF, false); // row_shr:4
    v = t < v ? t : v;
    t = (unsigned)__builtin_amdgcn_update_dpp(-1, (int)v, 0x118, 0xF, 0xF, false); // row_shr:8
    v = t < v ? t : v;
    t = (unsigned)__builtin_amdgcn_update_dpp(-1, (int)v, 0x142, 0xF, 0xF, false); // row_bcast:15
    v = t < v ? t : v;
    t = (unsigned)__builtin_amdgcn_update_dpp(-1, (int)v, 0x143, 0xF, 0xF, false); // row_bcast:31
    v = t < v ? t : v;
    return v;
}

// ROUND-11: r4's proven exchange protocol (publish b32 key -> raw s_barrier
// -> broadcast read -> pp[j] LDS read), UNCHANGED — r3 (solo) and r5
// (position-gather) both proved protocol restructuring loses. Change is
// TLP only: TPB 256 -> 512 (8 waves, 2/SIMD). Each wave's own scan issue
// halves (PT avg 5 -> 2.5) and the two waves per SIMD overlap each
// other's exchange-latency stalls; iteration wall ~= 520 fixed + 55 scan.
// Scalar px/py/pz arrays (v2f never packed, r3 post-mortem) allow odd PT:
// schedule PT 4/3/2/1, compaction at i = 509/1021/1533 (unvisited
// 1536/1024/512 = 512*PTnext). Ownership: idx = s*512+t, owner = j&511,
// slot = j>>9. Tie-break insensitivity of the sorted death multiset:
// HW-proven r3/r4/r5 (absmax=0 under three different tie-break orders).
template<int PT, bool FIRST, bool COMPACT>
__device__ __forceinline__ void prim_phase(
    const int t, const int lane, const int wid,
    const int i0, const int i1, const unsigned rem_in,
    float4* __restrict__ pp, float* __restrict__ deaths,
    unsigned* __restrict__ xslot, unsigned* __restrict__ wtot,
    float& pjx, float& pjy, float& pjz)
{
    float px[PT], py[PT], pz[PT];
    unsigned m[PT];
    unsigned vis = 0u;
#pragma unroll
    for (int s = 0; s < PT; ++s) {
        const int idx = s * TPB + t;
        float4 p = pp[idx];
        px[s] = p.x; py[s] = p.y; pz[s] = p.z;
        if (FIRST) {
            m[s] = 0x7F800000u | (unsigned)idx;           // +inf packed | idx
            if (idx >= (int)rem_in || idx == 0) vis |= 1u << s;  // pads + start
        } else {
            m[s] = __float_as_uint(p.w);                  // carried key
            if (idx >= (int)rem_in) vis |= 1u << s;       // empty slots
        }
    }

#pragma unroll 1
    for (int i = i0; i < i1; ++i) {
        unsigned lv0 = 0xFFFFFFFFu, lv1 = 0xFFFFFFFFu;
#pragma unroll
        for (int s = 0; s < PT; ++s) {
            float dx = px[s] - pjx, dy = py[s] - pjy, dz = pz[s] - pjz;
            float d2 = dx * dx + dy * dy + dz * dz;
            unsigned pk = (__float_as_uint(d2) & 0xFFFFF000u) | (unsigned)(s * TPB + t);
            unsigned nm = m[s] < pk ? m[s] : pk;
            m[s] = nm;
            unsigned ext = (unsigned)__builtin_amdgcn_sbfe((int)vis, s, 1);
            unsigned cand = nm | ext;
            if (s & 1) lv1 = lv1 < cand ? lv1 : cand;
            else       lv0 = lv0 < cand ? lv0 : cand;
        }
        unsigned lv = lv0 < lv1 ? lv0 : lv1;
        unsigned wmin = dpp_umin6(lv);           // valid in lane 63
        const int base = (i & 1) * NW;
        if (lane == 63) xslot[base + wid] = wmin;
        // raw barrier: publish write lands before post-release reads (DS
        // FIFO within CU) — HW-proven r2/r4/r5 (absmax=0).
        asm volatile("s_barrier" ::: "memory");
        const uint4 qa = *(const uint4*)&xslot[base];      // two independent
        const uint4 qb = *(const uint4*)&xslot[base + 4];  // b128 broadcast reads
        unsigned w01 = qa.x < qa.y ? qa.x : qa.y;
        unsigned w23 = qa.z < qa.w ? qa.z : qa.w;
        unsigned w45 = qb.x < qb.y ? qb.x : qb.y;
        unsigned w67 = qb.z < qb.w ? qb.z : qb.w;
        unsigned wA = w01 < w23 ? w01 : w23;
        unsigned wB = w45 < w67 ? w45 : w67;
        unsigned win = wA < wB ? wA : wB;
        int j = (int)(win & 0x7FFu);
        vis |= (t == (j & (TPB - 1))) ? (1u << (j >> 9)) : 0u;  // owner marks
        float4 pj = pp[j];                       // broadcast read, conflict-free
        pjx = pj.x; pjy = pj.y; pjz = pj.z;
        if (t == 0) deaths[i] = __uint_as_float(win & 0xFFFFF000u); // raw d2
    }

    if (COMPACT) {
        // block-wide compaction: survivors -> pp[0..rem_out) with keys in .w
        const unsigned livemask = ~vis & ((1u << PT) - 1u);
        const unsigned cnt = (unsigned)__popc(livemask);
        unsigned inc = cnt;
#pragma unroll
        for (int d = 1; d < 64; d <<= 1) {
            unsigned tt = (unsigned)__shfl_up((int)inc, d, 64);
            if (lane >= d) inc += tt;
        }
        if (lane == 63) wtot[wid] = inc;         // wave totals
        asm volatile("s_barrier" ::: "memory");  // wtot visible
        unsigned wbase = 0;
#pragma unroll
        for (int w = 0; w < NW; ++w) wbase += (w < wid) ? wtot[w] : 0u;
        unsigned dst = wbase + inc - cnt;        // exclusive prefix, block-wide
#pragma unroll
        for (int s = 0; s < PT; ++s) {
            if ((livemask >> s) & 1u) {
                pp[dst] = make_float4(px[s], py[s], pz[s],
                                      __uint_as_float((m[s] & 0xFFFFF000u) | dst));
                ++dst;
            }
        }
        asm volatile("s_barrier" ::: "memory");  // compacted pp visible to reload
    }
}

__global__ __launch_bounds__(TPB)
void topo_kernel(const float* __restrict__ pred,
                 const float* __restrict__ tgt,
                 float* __restrict__ topo /* [64][N_DEATH] */,
                 unsigned* __restrict__ ctr,
                 int fuse,
                 float* __restrict__ out) {
    __shared__ float4 pp[SORT_N];        // pos.xyz + (compacted) key in .w
    __shared__ float deaths[SORT_N];     // raw trunc d2 during Prim
    __shared__ __align__(16) unsigned xslot[2 * NW];  // [buf][wave]
    __shared__ unsigned wtot[NW];
    __shared__ unsigned lastflag;

    const int b = blockIdx.x;
    const float* x = (b < BATCH) ? (pred + b * LLEN) : (tgt + (b - BATCH) * LLEN);
    const int t = threadIdx.x;
    const int lane = t & 63;
    const int wid = t >> 6;

    // strided fill: idx = s*512+t, coalesced across t
#pragma unroll
    for (int s = 0; s < 4; ++s) {
        int idx = s * TPB + t;
        bool valid = idx < N_PTS;
        float vx = valid ? x[idx]     : 0.f;
        float vy = valid ? x[idx + 1] : 0.f;
        float vz = valid ? x[idx + 2] : 0.f;
        pp[idx] = make_float4(vx, vy, vz, 0.f);
    }
    __syncthreads();   // pp[] visible (real barrier)

    float pjx = x[0], pjy = x[1], pjz = x[2];

    // phase schedule: compact when unvisited-after == 512*PTnext
    prim_phase<4, true,  true >(t, lane, wid, 0,    509,  N_PTS, pp, deaths, xslot, wtot, pjx, pjy, pjz);
    prim_phase<3, false, true >(t, lane, wid, 509,  1021, 1536,  pp, deaths, xslot, wtot, pjx, pjy, pjz);
    prim_phase<2, false, true >(t, lane, wid, 1021, 1533, 1024,  pp, deaths, xslot, wtot, pjx, pjy, pjz);
    prim_phase<1, false, false>(t, lane, wid, 1533, 2045, 512,   pp, deaths, xslot, wtot, pjx, pjy, pjz);

    // pad then bitonic sort DESCENDING on trunc d2 (sqrt monotone)
    if (t < SORT_N - N_DEATH) deaths[N_DEATH + t] = -BIG;
    __syncthreads();

    for (int k = 2; k <= SORT_N; k <<= 1) {
        for (int jj = k >> 1; jj > 0; jj >>= 1) {
#pragma unroll
            for (int s = 0; s < SORT_N / TPB; ++s) {
                int ii = t + s * TPB;
                int ixj = ii ^ jj;
                if (ixj > ii) {
                    float a = deaths[ii], c = deaths[ixj];
                    bool descBlock = ((ii & k) == 0);
                    bool doSwap = descBlock ? (a < c) : (a > c);
                    if (doSwap) { deaths[ii] = c; deaths[ixj] = a; }
                }
            }
            __syncthreads();
        }
    }

    for (int e = t; e < N_DEATH; e += TPB)
        topo[b * N_DEATH + e] = sqrtf(deaths[e]);   // sqrt deferred to here

    if (!fuse) return;

    // ---- fused loss: last-finishing block computes the full reduction ----
    __syncthreads();
    if (t == 0) {
        __threadfence();   // release: make topo visible across XCDs
        unsigned prev = __hip_atomic_fetch_add(ctr, 1u, __ATOMIC_ACQ_REL,
                                               __HIP_MEMORY_SCOPE_AGENT);
        lastflag = (prev == 63u) ? 1u : 0u;
        __threadfence();   // acquire before cross-XCD reads
    }
    __syncthreads();
    if (lastflag == 0u) return;

    float msum = 0.f;
    const float4* p4 = (const float4*)pred;
    const float4* t4 = (const float4*)tgt;
    for (int e = t; e < (BATCH * LLEN) / 4; e += TPB) {   // 16384 float4 pairs
        float4 a = p4[e], c = t4[e];
        float dx = a.x - c.x, dy = a.y - c.y, dz = a.z - c.z, dw = a.w - c.w;
        msum += dx * dx + dy * dy + dz * dz + dw * dw;
    }
    float tsum = 0.f;
    const float4* q4 = (const float4*)topo;
    const int nt4 = (BATCH * N_DEATH) / 4;   // 16360
    for (int e = t; e < nt4; e += TPB) {
        float4 a = q4[e], c = q4[e + nt4];
        float dx = a.x - c.x, dy = a.y - c.y, dz = a.z - c.z, dw = a.w - c.w;
        tsum += dx * dx + dy * dy + dz * dz + dw * dw;
    }
    __shared__ float sm[2][NW];
#pragma unroll
    for (int off = 32; off >= 1; off >>= 1) {
        msum += __shfl_xor(msum, off);
        tsum += __shfl_xor(tsum, off);
    }
    if (lane == 0) { sm[0][wid] = msum; sm[1][wid] = tsum; }
    __syncthreads();
    if (t == 0) {
        float M = 0.f, T = 0.f;
#pragma unroll
        for (int w = 0; w < NW; ++w) { M += sm[0][w]; T += sm[1][w]; }
        out[0] = M / (float)(BATCH * LLEN) + 0.1f * (T / (float)(BATCH * N_DEATH));
    }
}

// Fallback: single-block deterministic reduction (if ws can't hold the counter)
#define RTPB 1024
__global__ __launch_bounds__(RTPB)
void loss_kernel(const float* __restrict__ pred,
                 const float* __restrict__ tgt,
                 const float* __restrict__ topo,
                 float* __restrict__ out) {
    const int t = threadIdx.x;
    float msum = 0.f;
    const float4* p4 = (const float4*)pred;
    const float4* t4 = (const float4*)tgt;
    const int n4 = (BATCH * LLEN) / 4;   // 16384
    for (int e = t; e < n4; e += RTPB) {
        float4 a = p4[e], c = t4[e];
        float dx = a.x - c.x, dy = a.y - c.y, dz = a.z - c.z, dw = a.w - c.w;
        msum += dx * dx + dy * dy + dz * dz + dw * dw;
    }
    float tsum = 0.f;
    const int nt = BATCH * N_DEATH;      // 65440
    for (int e = t; e < nt; e += RTPB) {
        float d = topo[e] - topo[e + nt];
        tsum += d * d;
    }
    __shared__ float sm[2][RTPB / 64];
#pragma unroll
    for (int off = 32; off >= 1; off >>= 1) {
        msum += __shfl_xor(msum, off);
        tsum += __shfl_xor(tsum, off);
    }
    int lane = t & 63, wid = t >> 6;
    if (lane == 0) { sm[0][wid] = msum; sm[1][wid] = tsum; }
    __syncthreads();
    if (t == 0) {
        float M = 0.f, T = 0.f;
#pragma unroll
        for (int w = 0; w < RTPB / 64; ++w) { M += sm[0][w]; T += sm[1][w]; }
        out[0] = M / (float)(BATCH * LLEN) + 0.1f * (T / (float)nt);
    }
}

extern "C" void kernel_launch(void* const* d_in, const int* in_sizes, int n_in,
                              void* d_out, int out_size, void* d_ws, size_t ws_size,
                              hipStream_t stream) {
    const float* pred = (const float*)d_in[0];
    const float* tgt  = (const float*)d_in[1];
    float* topo = (float*)d_ws;
    unsigned* ctr = (unsigned*)((char*)d_ws + TOPO_BYTES);
    const int fuse = (ws_size >= TOPO_BYTES + sizeof(unsigned)) ? 1 : 0;

    if (fuse) hipMemsetAsync(ctr, 0, sizeof(unsigned), stream);  // re-arm per replay

    topo_kernel<<<2 * BATCH, TPB, 0, stream>>>(pred, tgt, topo,
                                               fuse ? ctr : nullptr, fuse,
                                               (float*)d_out);
    if (!fuse)
        loss_kernel<<<1, RTPB, 0, stream>>>(pred, tgt, topo, (float*)d_out);
}

// Round 7
// 640.772 us; speedup vs baseline: 1.5745x; 1.0899x over previous
//
#include <hip/hip_runtime.h>
#include <math.h>

// Problem constants (reference: B=32, L=2048)
#define LLEN 2048
#define BATCH 32
#define N_PTS (LLEN - 2)     // 2046 embedded points
#define N_DEATH (LLEN - 3)   // 2045 MST edges / deaths
#define SORT_N 2048
#define TPB 256              // 4 waves — measured optimum (r3:1wv=1004cyc, r4:4wv=682, r6:8wv=765)
#define NW 4
#define BIG 1e30f
#define TOPO_BYTES ((size_t)64 * N_DEATH * 4)   // 523,520 B

// Wave64 unsigned-min via DPP (VALU pipe). Result valid in lane 63.
__device__ __forceinline__ unsigned dpp_umin6(unsigned v) {
    unsigned t;
    t = (unsigned)__builtin_amdgcn_update_dpp(-1, (int)v, 0x111, 0xF, 0xF, false); // row_shr:1
    v = t < v ? t : v;
    t = (unsigned)__builtin_amdgcn_update_dpp(-1, (int)v, 0x112, 0xF, 0xF, false); // row_shr:2
    v = t < v ? t : v;
    t = (unsigned)__builtin_amdgcn_update_dpp(-1, (int)v, 0x114, 0xF, 0xF, false); // row_shr:4
    v = t < v ? t : v;
    t = (unsigned)__builtin_amdgcn_update_dpp(-1, (int)v, 0x118, 0xF, 0xF, false); // row_shr:8
    v = t < v ? t : v;
    t = (unsigned)__builtin_amdgcn_update_dpp(-1, (int)v, 0x142, 0xF, 0xF, false); // row_bcast:15
    v = t < v ? t : v;
    t = (unsigned)__builtin_amdgcn_update_dpp(-1, (int)v, 0x143, 0xF, 0xF, false); // row_bcast:31
    v = t < v ? t : v;
    return v;
}

// ROUND-12: revert to r4 (TPB=256, proven protocol: publish b32 key ->
// raw s_barrier -> uint4 broadcast read -> pp[j] read; 682 cyc/iter =
// 522 fixed + 32*PT_avg) and apply the ONE proven lever harder: finer
// compaction. Schedule PT = 8/7/6/5/4/3/2/1, compacting whenever
// unvisited = 256*PT_next (i = 253/509/765/1021/1277/1533/1789).
// PT_avg 5.0 -> 4.50. Scalar px/py/pz arrays (r6-proven) allow odd PT.
// Protocol triangulation (r3 solo / r5 pos-gather / r6 8-wave) all lost:
// this protocol class at 4 waves is the measured optimum; only the scan
// term remains compressible.
template<int PT, bool FIRST, bool COMPACT>
__device__ __forceinline__ void prim_phase(
    const int t, const int lane, const int wid,
    const int i0, const int i1, const unsigned rem_in,
    float4* __restrict__ pp, float* __restrict__ deaths,
    unsigned* __restrict__ xslot, unsigned* __restrict__ wtot,
    float& pjx, float& pjy, float& pjz)
{
    float px[PT], py[PT], pz[PT];
    unsigned m[PT];
    unsigned vis = 0u;
#pragma unroll
    for (int s = 0; s < PT; ++s) {
        const int idx = s * TPB + t;
        float4 p = pp[idx];
        px[s] = p.x; py[s] = p.y; pz[s] = p.z;
        if (FIRST) {
            m[s] = 0x7F800000u | (unsigned)idx;           // +inf packed | idx
            if (idx >= (int)rem_in || idx == 0) vis |= 1u << s;  // pads + start
        } else {
            m[s] = __float_as_uint(p.w);                  // carried key
            if (idx >= (int)rem_in) vis |= 1u << s;       // empty slots (none in practice)
        }
    }

#pragma unroll 1
    for (int i = i0; i < i1; ++i) {
        unsigned lv0 = 0xFFFFFFFFu, lv1 = 0xFFFFFFFFu;
#pragma unroll
        for (int s = 0; s < PT; ++s) {
            float dx = px[s] - pjx, dy = py[s] - pjy, dz = pz[s] - pjz;
            float d2 = dx * dx + dy * dy + dz * dz;
            unsigned pk = (__float_as_uint(d2) & 0xFFFFF000u) | (unsigned)(s * TPB + t);
            unsigned nm = m[s] < pk ? m[s] : pk;
            m[s] = nm;
            unsigned ext = (unsigned)__builtin_amdgcn_sbfe((int)vis, s, 1);
            unsigned cand = nm | ext;
            if (s & 1) lv1 = lv1 < cand ? lv1 : cand;
            else       lv0 = lv0 < cand ? lv0 : cand;
        }
        unsigned lv = lv0 < lv1 ? lv0 : lv1;
        unsigned wmin = dpp_umin6(lv);           // valid in lane 63
        const int base = (i & 1) * NW;
        if (lane == 63) xslot[base + wid] = wmin;
        // raw barrier: publish write lands before post-release reads (DS
        // FIFO within CU) — HW-proven r2/r4/r5/r6 (absmax=0).
        asm volatile("s_barrier" ::: "memory");
        const uint4 q = *(const uint4*)&xslot[base];  // one b128 broadcast read
        unsigned w01 = q.x < q.y ? q.x : q.y;
        unsigned w23 = q.z < q.w ? q.z : q.w;
        unsigned win = w01 < w23 ? w01 : w23;
        int j = (int)(win & 0x7FFu);
        vis |= (t == (j & (TPB - 1))) ? (1u << (j >> 8)) : 0u;  // owner marks
        float4 pj = pp[j];                       // broadcast read, conflict-free
        pjx = pj.x; pjy = pj.y; pjz = pj.z;
        if (t == 0) deaths[i] = __uint_as_float(win & 0xFFFFF000u); // raw d2
    }

    if (COMPACT) {
        // block-wide compaction: survivors -> pp[0..rem_out) with keys in .w
        const unsigned livemask = ~vis & ((1u << PT) - 1u);
        const unsigned cnt = (unsigned)__popc(livemask);
        unsigned inc = cnt;
#pragma unroll
        for (int d = 1; d < 64; d <<= 1) {
            unsigned tt = (unsigned)__shfl_up((int)inc, d, 64);
            if (lane >= d) inc += tt;
        }
        if (lane == 63) wtot[wid] = inc;         // wave totals
        asm volatile("s_barrier" ::: "memory");  // wtot visible
        unsigned wbase = 0;
#pragma unroll
        for (int w = 0; w < NW; ++w) wbase += (w < wid) ? wtot[w] : 0u;
        unsigned dst = wbase + inc - cnt;        // exclusive prefix, block-wide
#pragma unroll
        for (int s = 0; s < PT; ++s) {
            if ((livemask >> s) & 1u) {
                pp[dst] = make_float4(px[s], py[s], pz[s],
                                      __uint_as_float((m[s] & 0xFFFFF000u) | dst));
                ++dst;
            }
        }
        asm volatile("s_barrier" ::: "memory");  // compacted pp visible to reload
    }
}

__global__ __launch_bounds__(TPB)
void topo_kernel(const float* __restrict__ pred,
                 const float* __restrict__ tgt,
                 float* __restrict__ topo /* [64][N_DEATH] */,
                 unsigned* __restrict__ ctr,
                 int fuse,
                 float* __restrict__ out) {
    __shared__ float4 pp[SORT_N];        // pos.xyz + (compacted) key in .w
    __shared__ float deaths[SORT_N];     // raw trunc d2 during Prim
    __shared__ __align__(16) unsigned xslot[2 * NW];  // [buf][wave]
    __shared__ unsigned wtot[NW];
    __shared__ unsigned lastflag;

    const int b = blockIdx.x;
    const float* x = (b < BATCH) ? (pred + b * LLEN) : (tgt + (b - BATCH) * LLEN);
    const int t = threadIdx.x;
    const int lane = t & 63;
    const int wid = t >> 6;

    // strided fill: idx = s*256+t, coalesced across t
#pragma unroll
    for (int s = 0; s < 8; ++s) {
        int idx = s * TPB + t;
        bool valid = idx < N_PTS;
        float vx = valid ? x[idx]     : 0.f;
        float vy = valid ? x[idx + 1] : 0.f;
        float vz = valid ? x[idx + 2] : 0.f;
        pp[idx] = make_float4(vx, vy, vz, 0.f);
    }
    __syncthreads();   // pp[] visible (real barrier)

    float pjx = x[0], pjy = x[1], pjz = x[2];

    // phase schedule: compact when unvisited-after == 256*PTnext
    // (unvisited before iter i = 2045 - i)
    prim_phase<8, true,  true >(t, lane, wid, 0,    253,  N_PTS, pp, deaths, xslot, wtot, pjx, pjy, pjz);
    prim_phase<7, false, true >(t, lane, wid, 253,  509,  1792,  pp, deaths, xslot, wtot, pjx, pjy, pjz);
    prim_phase<6, false, true >(t, lane, wid, 509,  765,  1536,  pp, deaths, xslot, wtot, pjx, pjy, pjz);
    prim_phase<5, false, true >(t, lane, wid, 765,  1021, 1280,  pp, deaths, xslot, wtot, pjx, pjy, pjz);
    prim_phase<4, false, true >(t, lane, wid, 1021, 1277, 1024,  pp, deaths, xslot, wtot, pjx, pjy, pjz);
    prim_phase<3, false, true >(t, lane, wid, 1277, 1533, 768,   pp, deaths, xslot, wtot, pjx, pjy, pjz);
    prim_phase<2, false, true >(t, lane, wid, 1533, 1789, 512,   pp, deaths, xslot, wtot, pjx, pjy, pjz);
    prim_phase<1, false, false>(t, lane, wid, 1789, 2045, 256,   pp, deaths, xslot, wtot, pjx, pjy, pjz);

    // pad then bitonic sort DESCENDING on trunc d2 (sqrt monotone)
    if (t < SORT_N - N_DEATH) deaths[N_DEATH + t] = -BIG;
    __syncthreads();

    for (int k = 2; k <= SORT_N; k <<= 1) {
        for (int jj = k >> 1; jj > 0; jj >>= 1) {
#pragma unroll
            for (int s = 0; s < SORT_N / TPB; ++s) {
                int ii = t + s * TPB;
                int ixj = ii ^ jj;
                if (ixj > ii) {
                    float a = deaths[ii], c = deaths[ixj];
                    bool descBlock = ((ii & k) == 0);
                    bool doSwap = descBlock ? (a < c) : (a > c);
                    if (doSwap) { deaths[ii] = c; deaths[ixj] = a; }
                }
            }
            __syncthreads();
        }
    }

    for (int e = t; e < N_DEATH; e += TPB)
        topo[b * N_DEATH + e] = sqrtf(deaths[e]);   // sqrt deferred to here

    if (!fuse) return;

    // ---- fused loss: last-finishing block computes the full reduction ----
    __syncthreads();
    if (t == 0) {
        __threadfence();   // release: make topo visible across XCDs
        unsigned prev = __hip_atomic_fetch_add(ctr, 1u, __ATOMIC_ACQ_REL,
                                               __HIP_MEMORY_SCOPE_AGENT);
        lastflag = (prev == 63u) ? 1u : 0u;
        __threadfence();   // acquire before cross-XCD reads
    }
    __syncthreads();
    if (lastflag == 0u) return;

    float msum = 0.f;
    const float4* p4 = (const float4*)pred;
    const float4* t4 = (const float4*)tgt;
    for (int e = t; e < (BATCH * LLEN) / 4; e += TPB) {   // 16384 float4 pairs
        float4 a = p4[e], c = t4[e];
        float dx = a.x - c.x, dy = a.y - c.y, dz = a.z - c.z, dw = a.w - c.w;
        msum += dx * dx + dy * dy + dz * dz + dw * dw;
    }
    float tsum = 0.f;
    const float4* q4 = (const float4*)topo;
    const int nt4 = (BATCH * N_DEATH) / 4;   // 16360
    for (int e = t; e < nt4; e += TPB) {
        float4 a = q4[e], c = q4[e + nt4];
        float dx = a.x - c.x, dy = a.y - c.y, dz = a.z - c.z, dw = a.w - c.w;
        tsum += dx * dx + dy * dy + dz * dz + dw * dw;
    }
    __shared__ float sm[2][NW];
#pragma unroll
    for (int off = 32; off >= 1; off >>= 1) {
        msum += __shfl_xor(msum, off);
        tsum += __shfl_xor(tsum, off);
    }
    if (lane == 0) { sm[0][wid] = msum; sm[1][wid] = tsum; }
    __syncthreads();
    if (t == 0) {
        float M = 0.f, T = 0.f;
#pragma unroll
        for (int w = 0; w < NW; ++w) { M += sm[0][w]; T += sm[1][w]; }
        out[0] = M / (float)(BATCH * LLEN) + 0.1f * (T / (float)(BATCH * N_DEATH));
    }
}

// Fallback: single-block deterministic reduction (if ws can't hold the counter)
#define RTPB 1024
__global__ __launch_bounds__(RTPB)
void loss_kernel(const float* __restrict__ pred,
                 const float* __restrict__ tgt,
                 const float* __restrict__ topo,
                 float* __restrict__ out) {
    const int t = threadIdx.x;
    float msum = 0.f;
    const float4* p4 = (const float4*)pred;
    const float4* t4 = (const float4*)tgt;
    const int n4 = (BATCH * LLEN) / 4;   // 16384
    for (int e = t; e < n4; e += RTPB) {
        float4 a = p4[e], c = t4[e];
        float dx = a.x - c.x, dy = a.y - c.y, dz = a.z - c.z, dw = a.w - c.w;
        msum += dx * dx + dy * dy + dz * dz + dw * dw;
    }
    float tsum = 0.f;
    const int nt = BATCH * N_DEATH;      // 65440
    for (int e = t; e < nt; e += RTPB) {
        float d = topo[e] - topo[e + nt];
        tsum += d * d;
    }
    __shared__ float sm[2][RTPB / 64];
#pragma unroll
    for (int off = 32; off >= 1; off >>= 1) {
        msum += __shfl_xor(msum, off);
        tsum += __shfl_xor(tsum, off);
    }
    int lane = t & 63, wid = t >> 6;
    if (lane == 0) { sm[0][wid] = msum; sm[1][wid] = tsum; }
    __syncthreads();
    if (t == 0) {
        float M = 0.f, T = 0.f;
#pragma unroll
        for (int w = 0; w < RTPB / 64; ++w) { M += sm[0][w]; T += sm[1][w]; }
        out[0] = M / (float)(BATCH * LLEN) + 0.1f * (T / (float)nt);
    }
}

extern "C" void kernel_launch(void* const* d_in, const int* in_sizes, int n_in,
                              void* d_out, int out_size, void* d_ws, size_t ws_size,
                              hipStream_t stream) {
    const float* pred = (const float*)d_in[0];
    const float* tgt  = (const float*)d_in[1];
    float* topo = (float*)d_ws;
    unsigned* ctr = (unsigned*)((char*)d_ws + TOPO_BYTES);
    const int fuse = (ws_size >= TOPO_BYTES + sizeof(unsigned)) ? 1 : 0;

    if (fuse) hipMemsetAsync(ctr, 0, sizeof(unsigned), stream);  // re-arm per replay

    topo_kernel<<<2 * BATCH, TPB, 0, stream>>>(pred, tgt, topo,
                                               fuse ? ctr : nullptr, fuse,
                                               (float*)d_out);
    if (!fuse)
        loss_kernel<<<1, RTPB, 0, stream>>>(pred, tgt, topo, (float*)d_out);
}

// Round 8
// 631.876 us; speedup vs baseline: 1.5967x; 1.0141x over previous
//
#include <hip/hip_runtime.h>
#include <math.h>

// Problem constants (reference: B=32, L=2048)
#define LLEN 2048
#define BATCH 32
#define N_PTS (LLEN - 2)     // 2046 embedded points
#define N_DEATH (LLEN - 3)   // 2045 MST edges / deaths
#define SORT_N 2048
#define TPB 256              // 4 waves — measured optimum (r3:1wv, r4:4wv=682cyc/iter, r6:8wv=765)
#define NW 4
#define BIG 1e30f
#define TOPO_BYTES ((size_t)64 * N_DEATH * 4)   // 523,520 B

typedef float v2f __attribute__((ext_vector_type(2)));

// Wave64 unsigned-min via DPP (VALU pipe). Result valid in lane 63.
__device__ __forceinline__ unsigned dpp_umin6(unsigned v) {
    unsigned t;
    t = (unsigned)__builtin_amdgcn_update_dpp(-1, (int)v, 0x111, 0xF, 0xF, false); // row_shr:1
    v = t < v ? t : v;
    t = (unsigned)__builtin_amdgcn_update_dpp(-1, (int)v, 0x112, 0xF, 0xF, false); // row_shr:2
    v = t < v ? t : v;
    t = (unsigned)__builtin_amdgcn_update_dpp(-1, (int)v, 0x114, 0xF, 0xF, false); // row_shr:4
    v = t < v ? t : v;
    t = (unsigned)__builtin_amdgcn_update_dpp(-1, (int)v, 0x118, 0xF, 0xF, false); // row_shr:8
    v = t < v ? t : v;
    t = (unsigned)__builtin_amdgcn_update_dpp(-1, (int)v, 0x142, 0xF, 0xF, false); // row_bcast:15
    v = t < v ? t : v;
    t = (unsigned)__builtin_amdgcn_update_dpp(-1, (int)v, 0x143, 0xF, 0xF, false); // row_bcast:31
    v = t < v ? t : v;
    return v;
}

// ROUND-13 (FINAL): exact revert to the r4/ROUND-9 champion (581.9 us topo,
// 630.7 total). Search-space triangulation complete:
//   r3 solo-wave (-195), r5 position-publish (-379), r6 8-wave TLP (-71),
//   r7 fine compaction (-12) all lost; r1/r2/r4 wins are all incorporated.
// Calibrated chain: 682 cyc/iter = ~520 fixed (2 dependent LDS round-trips
// + raw s_barrier + DPP reduce) + 31*PT_avg scan, PT_avg = 5.0 at the
// measured-optimal 8/6/4/2 compaction schedule. Not a HW roofline
// (VALU 9%, HBM 0.03%) — it is the latency floor of the serial Prim
// protocol family explored here.
template<int PT, bool FIRST, bool COMPACT>
__device__ __forceinline__ void prim_phase(
    const int t, const int lane, const int wid,
    const int i0, const int i1, const unsigned rem_in,
    float4* __restrict__ pp, float* __restrict__ deaths,
    unsigned* __restrict__ xslot, unsigned* __restrict__ wtot,
    float& pjx, float& pjy, float& pjz)
{
    v2f px2[PT / 2], py2[PT / 2], pz2[PT / 2];
    unsigned m[PT];
    unsigned vis = 0u;
#pragma unroll
    for (int s = 0; s < PT; ++s) {
        const int idx = s * 256 + t;
        float4 p = pp[idx];
        if (s & 1) { px2[s >> 1].y = p.x; py2[s >> 1].y = p.y; pz2[s >> 1].y = p.z; }
        else       { px2[s >> 1].x = p.x; py2[s >> 1].x = p.y; pz2[s >> 1].x = p.z; }
        if (FIRST) {
            m[s] = 0x7F800000u | (unsigned)idx;           // +inf packed | idx
            if (idx >= (int)rem_in || idx == 0) vis |= 1u << s;  // pads + start
        } else {
            m[s] = __float_as_uint(p.w);                  // carried key
            if (idx >= (int)rem_in) vis |= 1u << s;       // empty slots
        }
    }

#pragma unroll 1
    for (int i = i0; i < i1; ++i) {
        v2f jx = {pjx, pjx}, jy = {pjy, pjy}, jz = {pjz, pjz};
        unsigned lv0 = 0xFFFFFFFFu, lv1 = 0xFFFFFFFFu;
#pragma unroll
        for (int k = 0; k < PT / 2; ++k) {
            v2f dx = px2[k] - jx, dy = py2[k] - jy, dz = pz2[k] - jz;
            v2f d2 = dx * dx + dy * dy + dz * dz;
            unsigned pk0 = (__float_as_uint(d2.x) & 0xFFFFF000u) | (unsigned)((2 * k) * 256 + t);
            unsigned pk1 = (__float_as_uint(d2.y) & 0xFFFFF000u) | (unsigned)((2 * k + 1) * 256 + t);
            unsigned nm0 = m[2 * k] < pk0 ? m[2 * k] : pk0;
            unsigned nm1 = m[2 * k + 1] < pk1 ? m[2 * k + 1] : pk1;
            m[2 * k] = nm0;
            m[2 * k + 1] = nm1;
            unsigned e0 = (unsigned)__builtin_amdgcn_sbfe((int)vis, 2 * k, 1);
            unsigned e1 = (unsigned)__builtin_amdgcn_sbfe((int)vis, 2 * k + 1, 1);
            unsigned c0 = nm0 | e0, c1 = nm1 | e1;
            lv0 = lv0 < c0 ? lv0 : c0;
            lv1 = lv1 < c1 ? lv1 : c1;
        }
        unsigned lv = lv0 < lv1 ? lv0 : lv1;
        unsigned wmin = dpp_umin6(lv);           // valid in lane 63
        const int base = (i & 1) * NW;
        if (lane == 63) xslot[base + wid] = wmin;
        // raw barrier: publish write lands before post-release reads (DS
        // FIFO within CU) — pattern HW-proven in r2/r4/r5/r6/r7 (absmax=0).
        asm volatile("s_barrier" ::: "memory");
        const uint4 q = *(const uint4*)&xslot[base];  // one b128 broadcast read
        unsigned w01 = q.x < q.y ? q.x : q.y;
        unsigned w23 = q.z < q.w ? q.z : q.w;
        unsigned win = w01 < w23 ? w01 : w23;
        int j = (int)(win & 0x7FFu);
        vis |= (t == (j & 255)) ? (1u << (j >> 8)) : 0u;   // owner marks visited
        float4 pj = pp[j];                       // broadcast read, conflict-free
        pjx = pj.x; pjy = pj.y; pjz = pj.z;
        if (t == 0) deaths[i] = __uint_as_float(win & 0xFFFFF000u); // raw d2
    }

    if (COMPACT) {
        // block-wide compaction: survivors -> pp[0..rem_out) with keys in .w
        const unsigned livemask = ~vis & ((1u << PT) - 1u);
        const unsigned cnt = (unsigned)__popc(livemask);
        unsigned inc = cnt;
#pragma unroll
        for (int d = 1; d < 64; d <<= 1) {
            unsigned tt = (unsigned)__shfl_up((int)inc, d, 64);
            if (lane >= d) inc += tt;
        }
        if (lane == 63) wtot[wid] = inc;         // wave totals
        asm volatile("s_barrier" ::: "memory");  // wtot visible
        unsigned wbase = 0;
#pragma unroll
        for (int w = 0; w < NW; ++w) wbase += (w < wid) ? wtot[w] : 0u;
        unsigned dst = wbase + inc - cnt;        // exclusive prefix, block-wide
#pragma unroll
        for (int s = 0; s < PT; ++s) {
            if ((livemask >> s) & 1u) {
                float xx = (s & 1) ? px2[s >> 1].y : px2[s >> 1].x;
                float yy = (s & 1) ? py2[s >> 1].y : py2[s >> 1].x;
                float zz = (s & 1) ? pz2[s >> 1].y : pz2[s >> 1].x;
                pp[dst] = make_float4(xx, yy, zz,
                                      __uint_as_float((m[s] & 0xFFFFF000u) | dst));
                ++dst;
            }
        }
        asm volatile("s_barrier" ::: "memory");  // compacted pp visible to reload
    }
}

__global__ __launch_bounds__(TPB)
void topo_kernel(const float* __restrict__ pred,
                 const float* __restrict__ tgt,
                 float* __restrict__ topo /* [64][N_DEATH] */,
                 unsigned* __restrict__ ctr,
                 int fuse,
                 float* __restrict__ out) {
    __shared__ float4 pp[SORT_N];        // pos.xyz + (compacted) key in .w
    __shared__ float deaths[SORT_N];     // raw trunc d2 during Prim
    __shared__ __align__(16) unsigned xslot[2 * NW];  // [buf][wave]
    __shared__ unsigned wtot[NW];
    __shared__ unsigned lastflag;

    const int b = blockIdx.x;
    const float* x = (b < BATCH) ? (pred + b * LLEN) : (tgt + (b - BATCH) * LLEN);
    const int t = threadIdx.x;
    const int lane = t & 63;
    const int wid = t >> 6;

    // strided fill: idx = s*256+t, coalesced across t
#pragma unroll
    for (int s = 0; s < 8; ++s) {
        int idx = s * 256 + t;
        bool valid = idx < N_PTS;
        float vx = valid ? x[idx]     : 0.f;
        float vy = valid ? x[idx + 1] : 0.f;
        float vz = valid ? x[idx + 2] : 0.f;
        pp[idx] = make_float4(vx, vy, vz, 0.f);
    }
    __syncthreads();   // pp[] visible (real barrier)

    float pjx = x[0], pjy = x[1], pjz = x[2];

    // phase schedule: compact when unvisited-after == 256*PTnext
    prim_phase<8, true,  true >(t, lane, wid, 0,    509,  N_PTS, pp, deaths, xslot, wtot, pjx, pjy, pjz);
    prim_phase<6, false, true >(t, lane, wid, 509,  1021, 1536,  pp, deaths, xslot, wtot, pjx, pjy, pjz);
    prim_phase<4, false, true >(t, lane, wid, 1021, 1533, 1024,  pp, deaths, xslot, wtot, pjx, pjy, pjz);
    prim_phase<2, false, false>(t, lane, wid, 1533, 2045, 512,   pp, deaths, xslot, wtot, pjx, pjy, pjz);

    // pad then bitonic sort DESCENDING on trunc d2 (sqrt monotone)
    if (t < SORT_N - N_DEATH) deaths[N_DEATH + t] = -BIG;
    __syncthreads();

    for (int k = 2; k <= SORT_N; k <<= 1) {
        for (int jj = k >> 1; jj > 0; jj >>= 1) {
#pragma unroll
            for (int s = 0; s < SORT_N / TPB; ++s) {
                int ii = t + s * TPB;
                int ixj = ii ^ jj;
                if (ixj > ii) {
                    float a = deaths[ii], c = deaths[ixj];
                    bool descBlock = ((ii & k) == 0);
                    bool doSwap = descBlock ? (a < c) : (a > c);
                    if (doSwap) { deaths[ii] = c; deaths[ixj] = a; }
                }
            }
            __syncthreads();
        }
    }

    for (int e = t; e < N_DEATH; e += TPB)
        topo[b * N_DEATH + e] = sqrtf(deaths[e]);   // sqrt deferred to here

    if (!fuse) return;

    // ---- fused loss: last-finishing block computes the full reduction ----
    __syncthreads();
    if (t == 0) {
        __threadfence();   // release: make topo visible across XCDs
        unsigned prev = __hip_atomic_fetch_add(ctr, 1u, __ATOMIC_ACQ_REL,
                                               __HIP_MEMORY_SCOPE_AGENT);
        lastflag = (prev == 63u) ? 1u : 0u;
        __threadfence();   // acquire before cross-XCD reads
    }
    __syncthreads();
    if (lastflag == 0u) return;

    float msum = 0.f;
    const float4* p4 = (const float4*)pred;
    const float4* t4 = (const float4*)tgt;
    for (int e = t; e < (BATCH * LLEN) / 4; e += TPB) {   // 16384 float4 pairs
        float4 a = p4[e], c = t4[e];
        float dx = a.x - c.x, dy = a.y - c.y, dz = a.z - c.z, dw = a.w - c.w;
        msum += dx * dx + dy * dy + dz * dz + dw * dw;
    }
    float tsum = 0.f;
    const float4* q4 = (const float4*)topo;
    const int nt4 = (BATCH * N_DEATH) / 4;   // 16360
    for (int e = t; e < nt4; e += TPB) {
        float4 a = q4[e], c = q4[e + nt4];
        float dx = a.x - c.x, dy = a.y - c.y, dz = a.z - c.z, dw = a.w - c.w;
        tsum += dx * dx + dy * dy + dz * dz + dw * dw;
    }
    __shared__ float sm[2][NW];
#pragma unroll
    for (int off = 32; off >= 1; off >>= 1) {
        msum += __shfl_xor(msum, off);
        tsum += __shfl_xor(tsum, off);
    }
    if (lane == 0) { sm[0][wid] = msum; sm[1][wid] = tsum; }
    __syncthreads();
    if (t == 0) {
        float M = 0.f, T = 0.f;
#pragma unroll
        for (int w = 0; w < NW; ++w) { M += sm[0][w]; T += sm[1][w]; }
        out[0] = M / (float)(BATCH * LLEN) + 0.1f * (T / (float)(BATCH * N_DEATH));
    }
}

// Fallback: single-block deterministic reduction (if ws can't hold the counter)
#define RTPB 1024
__global__ __launch_bounds__(RTPB)
void loss_kernel(const float* __restrict__ pred,
                 const float* __restrict__ tgt,
                 const float* __restrict__ topo,
                 float* __restrict__ out) {
    const int t = threadIdx.x;
    float msum = 0.f;
    const float4* p4 = (const float4*)pred;
    const float4* t4 = (const float4*)tgt;
    const int n4 = (BATCH * LLEN) / 4;   // 16384
    for (int e = t; e < n4; e += RTPB) {
        float4 a = p4[e], c = t4[e];
        float dx = a.x - c.x, dy = a.y - c.y, dz = a.z - c.z, dw = a.w - c.w;
        msum += dx * dx + dy * dy + dz * dz + dw * dw;
    }
    float tsum = 0.f;
    const int nt = BATCH * N_DEATH;      // 65440
    for (int e = t; e < nt; e += RTPB) {
        float d = topo[e] - topo[e + nt];
        tsum += d * d;
    }
    __shared__ float sm[2][RTPB / 64];
#pragma unroll
    for (int off = 32; off >= 1; off >>= 1) {
        msum += __shfl_xor(msum, off);
        tsum += __shfl_xor(tsum, off);
    }
    int lane = t & 63, wid = t >> 6;
    if (lane == 0) { sm[0][wid] = msum; sm[1][wid] = tsum; }
    __syncthreads();
    if (t == 0) {
        float M = 0.f, T = 0.f;
#pragma unroll
        for (int w = 0; w < RTPB / 64; ++w) { M += sm[0][w]; T += sm[1][w]; }
        out[0] = M / (float)(BATCH * LLEN) + 0.1f * (T / (float)nt);
    }
}

extern "C" void kernel_launch(void* const* d_in, const int* in_sizes, int n_in,
                              void* d_out, int out_size, void* d_ws, size_t ws_size,
                              hipStream_t stream) {
    const float* pred = (const float*)d_in[0];
    const float* tgt  = (const float*)d_in[1];
    float* topo = (float*)d_ws;
    unsigned* ctr = (unsigned*)((char*)d_ws + TOPO_BYTES);
    const int fuse = (ws_size >= TOPO_BYTES + sizeof(unsigned)) ? 1 : 0;

    if (fuse) hipMemsetAsync(ctr, 0, sizeof(unsigned), stream);  // re-arm per replay

    topo_kernel<<<2 * BATCH, TPB, 0, stream>>>(pred, tgt, topo,
                                               fuse ? ctr : nullptr, fuse,
                                               (float*)d_out);
    if (!fuse)
        loss_kernel<<<1, RTPB, 0, stream>>>(pred, tgt, topo, (float*)d_out);
}